// Round 3
// baseline (363.842 us; speedup 1.0000x reference)
//
#include <hip/hip_runtime.h>
#include <cmath>

#define D_IN 256
#define H_DIM 128
#define NUM_GRAPHS 1024
#define CHUNK 512
#define SUBT 64
#define NSUBT (CHUNK / SUBT)
#define MAXSEG 16
#define REC_F 768  // floats per record: ewsum[256], ssum[256], mx[256]

typedef __attribute__((ext_vector_type(8))) __bf16 bf16x8;
typedef __attribute__((ext_vector_type(4))) float f32x4;
typedef __attribute__((ext_vector_type(4))) unsigned short ushort4v;

__device__ inline float b2f(unsigned short u) {
    unsigned int x = ((unsigned int)u) << 16;
    return __builtin_bit_cast(float, x);
}

// ---------------------------------------------------------------------------
// Pack W1 (f32 [256][128]) into bf16 MFMA B-fragment order.
// B-frag for mfma_f32_16x16x32_bf16: lane l holds B[k][n], n = nt*16 + (l&15),
// k = ks*32 + (l>>4)*8 + i. packed[((nt*8+ks)*64 + l)*8 + i]
// ---------------------------------------------------------------------------
__global__ void pack_w1(const float* __restrict__ W1, ushort* __restrict__ packed) {
    int tid = blockIdx.x * 256 + threadIdx.x;
    if (tid >= 8 * 8 * 64) return;
    int nt = tid >> 9;
    int ks = (tid >> 6) & 7;
    int l = tid & 63;
    int col = nt * 16 + (l & 15);
    int kbase = ks * 32 + ((l >> 4) & 3) * 8;
#pragma unroll
    for (int i = 0; i < 8; ++i) {
        float v = W1[(size_t)(kbase + i) * H_DIM + col];
        __bf16 b = (__bf16)v;
        packed[(size_t)tid * 8 + i] = __builtin_bit_cast(unsigned short, b);
    }
}

// ---------------------------------------------------------------------------
// Fused: stage x sub-tile to LDS (bf16, swizzled) -> MFMA scores from LDS ->
// pool from LDS. Per-wave independent segment flush (no barriers in pool).
// ---------------------------------------------------------------------------
__global__ __launch_bounds__(256, 4) void fused_kernel(
    const float* __restrict__ x, const ushort* __restrict__ w1p,
    const float* __restrict__ b1, const float* __restrict__ W2,
    const float* __restrict__ b2, const int* __restrict__ batch,
    float* __restrict__ recs, int2* __restrict__ hdr,
    float* __restrict__ zpart, int N) {
    int tid = threadIdx.x;
    int l = tid & 63;
    int w = tid >> 6;
    int r16 = l & 15;
    int kg = l >> 4;
    int blk = blockIdx.x;
    long long base = (long long)blk * CHUNK;
    int chunkN = (int)min((long long)CHUNK, (long long)N - base);

    __shared__ ushort sx[SUBT * D_IN];  // 32 KB bf16, XOR-swizzled @16B
    __shared__ float escore[SUBT];
    __shared__ int sbatch[CHUNK];
    __shared__ int seglist[MAXSEG + 1];
    __shared__ int snseg;

    if (tid < MAXSEG) hdr[blk * MAXSEG + tid] = make_int2(-1, 0);

    for (int i = tid; i < chunkN; i += 256) sbatch[i] = batch[base + i];
    __syncthreads();

    // segment boundary scan (wave 0, ballot-compaction)
    if (tid < 64) {
        int nseg = 0;
        for (int t0 = 0; t0 < chunkN; t0 += 64) {
            int i = t0 + l;
            bool flag = (i < chunkN) && (i == 0 || sbatch[i] != sbatch[i - 1]);
            unsigned long long m = __ballot(flag);
            if (l == 0) {
                while (m) {
                    int b = __ffsll(m) - 1;
                    if (nseg < MAXSEG) seglist[nseg] = t0 + b;
                    nseg++;
                    m &= m - 1;
                }
            }
            nseg = __shfl(nseg, 0, 64);
        }
        if (l == 0) {
            if (nseg > MAXSEG) nseg = MAXSEG;
            snseg = nseg;
            seglist[nseg] = chunkN;
        }
    }
    __syncthreads();

    // hoisted epilogue weights
    float w2v[8], b1v[8];
#pragma unroll
    for (int nt = 0; nt < 8; ++nt) {
        int c = nt * 16 + r16;
        w2v[nt] = W2[c];
        b1v[nt] = b1[c];
    }
    float bb = b2[0];
    int nsegL = snseg;

    f32x4 asum = {0.f, 0.f, 0.f, 0.f};
    f32x4 ssum = {0.f, 0.f, 0.f, 0.f};
    f32x4 mx = {-INFINITY, -INFINITY, -INFINITY, -INFINITY};
    float zacc = 0.f;
    int curseg = 0;

    for (int t = 0; t < NSUBT; ++t) {
        if (t * SUBT >= chunkN) break;  // uniform

        // ---- STAGE: 64 rows x 256 cols f32 -> bf16 LDS (swizzled) ----
        // iter k: wave handles row 4k + w, lanes cover the full 1KB row.
        {
            int row = w;  // + 4k per iter
#pragma unroll
            for (int k = 0; k < 16; ++k, row += 4) {
                long long grow = base + t * SUBT + row;
                if (grow >= N) grow = N - 1;
                f32x4 u = *(const f32x4*)(x + grow * D_IN + l * 4);
                ushort4v pk;
#pragma unroll
                for (int j = 0; j < 4; ++j)
                    pk[j] = __builtin_bit_cast(unsigned short, (__bf16)u[j]);
                unsigned addr = ((unsigned)(row * 512 + l * 8)) ^ ((row & 7) << 4);
                *(ushort4v*)((char*)sx + addr) = pk;
            }
        }
        __syncthreads();

        // ---- SCORE: MFMA from LDS A-frags + global (L2-hot) B-frags ----
        long long rowBase = base + t * SUBT + w * 16;
        int rl = w * 16 + r16;  // LDS row for A-frag
        unsigned abase = ((unsigned)(rl * 512 + kg * 16)) ;
        f32x4 acc[8] = {};
#pragma unroll
        for (int ks = 0; ks < 8; ++ks) {
            bf16x8 af = *(const bf16x8*)((const char*)sx +
                          ((abase + ks * 64) ^ ((rl & 7) << 4)));
#pragma unroll
            for (int nt = 0; nt < 8; ++nt) {
                bf16x8 bfw = *(const bf16x8*)(w1p + ((size_t)(nt * 8 + ks) * 64 + l) * 8);
                acc[nt] = __builtin_amdgcn_mfma_f32_16x16x32_bf16(af, bfw, acc[nt], 0, 0, 0);
            }
        }
#pragma unroll
        for (int reg = 0; reg < 4; ++reg) {
            float p = 0.f;
#pragma unroll
            for (int nt = 0; nt < 8; ++nt) {
                float h = acc[nt][reg] + b1v[nt];
                p += fmaxf(h, 0.f) * w2v[nt];
            }
            p += __shfl_xor(p, 1, 64);
            p += __shfl_xor(p, 2, 64);
            p += __shfl_xor(p, 4, 64);
            p += __shfl_xor(p, 8, 64);
            long long row = rowBase + kg * 4 + reg;
            if (r16 == 0) {
                int li = w * 16 + kg * 4 + reg;
                escore[li] = (row < N) ? __expf(p + bb) : 0.f;
            }
        }
        __syncthreads();

        if (tid < SUBT) zacc += escore[tid];

        // ---- POOL from LDS; per-wave rows i == w (mod 4); no barriers ----
        int tlo = t * SUBT, thi = min(t * SUBT + SUBT, chunkN);
        while (tlo < thi) {
            int s1 = seglist[curseg + 1];
            int hi = min(s1, thi);
            for (int i = tlo + ((w - tlo) & 3); i < hi; i += 4) {
                int lr = i & 63;
                unsigned addr = ((unsigned)(lr * 512 + l * 8)) ^ ((lr & 7) << 4);
                ushort4v h = *(const ushort4v*)((const char*)sx + addr);
                float wgt = escore[lr];
#pragma unroll
                for (int j = 0; j < 4; ++j) {
                    float v = b2f(h[j]);
                    asum[j] += v * wgt;
                    ssum[j] += v;
                    mx[j] = fmaxf(mx[j], v);
                }
            }
            if (hi == s1 && curseg < nsegL) {
                // per-wave flush: wave w's 64 lanes hold a full 256-col partial
                float* rb = recs + ((size_t)(blk * MAXSEG + curseg) * 4 + w) * REC_F;
                *(f32x4*)(rb + l * 4) = asum;
                *(f32x4*)(rb + 256 + l * 4) = ssum;
                *(f32x4*)(rb + 512 + l * 4) = mx;
                if (tid == 0)
                    hdr[blk * MAXSEG + curseg] =
                        make_int2(sbatch[seglist[curseg]], s1 - seglist[curseg]);
#pragma unroll
                for (int j = 0; j < 4; ++j) {
                    asum[j] = 0.f;
                    ssum[j] = 0.f;
                    mx[j] = -INFINITY;
                }
                curseg++;
            }
            tlo = hi;
        }
        __syncthreads();  // LDS x + escore reused next sub-tile
    }

    // block z partial
    if (tid < 64) {
        zacc += __shfl_xor(zacc, 32, 64);
        zacc += __shfl_xor(zacc, 16, 64);
        zacc += __shfl_xor(zacc, 8, 64);
        zacc += __shfl_xor(zacc, 4, 64);
        zacc += __shfl_xor(zacc, 2, 64);
        zacc += __shfl_xor(zacc, 1, 64);
        if (l == 0) zpart[blk] = zacc;
    }
}

// ---------------------------------------------------------------------------
__device__ inline int lower_bound_i(const int* __restrict__ arr, int n, int val) {
    int lo = 0, hi = n;
    while (lo < hi) {
        int mid = (lo + hi) >> 1;
        if (arr[mid] < val) lo = mid + 1; else hi = mid;
    }
    return lo;
}

// One block per graph: merge per-wave partial records, normalize, write out.
__global__ __launch_bounds__(256) void combine_kernel(
    const float* __restrict__ recs, const int2* __restrict__ hdr,
    const float* __restrict__ zpart, int nblk,
    const int* __restrict__ batch, int N, float* __restrict__ out) {
    int g = blockIdx.x;
    int tid = threadIdx.x;

    __shared__ float szr[256];
    float zs = 0.f;
    for (int i = tid; i < nblk; i += 256) zs += zpart[i];
    szr[tid] = zs;
    __syncthreads();
    for (int off = 128; off > 0; off >>= 1) {
        if (tid < off) szr[tid] += szr[tid + off];
        __syncthreads();
    }
    float invZ = 1.f / szr[0];

    __shared__ int sb[2];
    if (tid < 2) sb[tid] = lower_bound_i(batch, N, g + tid);
    __syncthreads();
    int start = sb[0], end = sb[1];

    float ew = 0.f, ss = 0.f, mxv = -INFINITY;
    int cnt = 0;
    if (end > start) {
        int b0 = start / CHUNK, b1 = (end - 1) / CHUNK;
        for (int b = b0; b <= b1; ++b) {
            for (int si = 0; si < MAXSEG; ++si) {
                int2 h = hdr[b * MAXSEG + si];
                if (h.x == g) {
                    const float* rbb = recs + (size_t)(b * MAXSEG + si) * 4 * REC_F;
#pragma unroll
                    for (int wv = 0; wv < 4; ++wv) {
                        const float* rb = rbb + wv * REC_F;
                        ew += rb[tid];
                        ss += rb[256 + tid];
                        mxv = fmaxf(mxv, rb[512 + tid]);
                    }
                    cnt += h.y;
                }
            }
        }
    }
    size_t ob = (size_t)g * (3 * D_IN);
    out[ob + tid] = ew * invZ;
    out[ob + D_IN + tid] = (cnt > 0) ? mxv : 0.f;
    out[ob + 2 * D_IN + tid] = ss / (float)max(cnt, 1);
}

// ---------------------------------------------------------------------------
extern "C" void kernel_launch(void* const* d_in, const int* in_sizes, int n_in,
                              void* d_out, int out_size, void* d_ws, size_t ws_size,
                              hipStream_t stream) {
    const float* x = (const float*)d_in[0];
    const float* W1 = (const float*)d_in[1];
    const float* b1 = (const float*)d_in[2];
    const float* W2 = (const float*)d_in[3];
    const float* b2 = (const float*)d_in[4];
    const int* batch = (const int*)d_in[5];
    int N = in_sizes[0] / D_IN;
    float* out = (float*)d_out;
    int NB = (N + CHUNK - 1) / CHUNK;

    char* ws = (char*)d_ws;
    size_t off = 0;
    ushort* w1p = (ushort*)(ws + off);
    off += 8 * 8 * 64 * 8 * sizeof(ushort);  // 64 KB
    off = (off + 255) & ~(size_t)255;
    float* recs = (float*)(ws + off);
    off += (size_t)NB * MAXSEG * 4 * REC_F * sizeof(float);  // ~192 MB
    off = (off + 255) & ~(size_t)255;
    int2* hdr = (int2*)(ws + off);
    off += (size_t)NB * MAXSEG * sizeof(int2);
    off = (off + 255) & ~(size_t)255;
    float* zpart = (float*)(ws + off);
    off += (size_t)NB * sizeof(float);

    pack_w1<<<16, 256, 0, stream>>>(W1, w1p);
    fused_kernel<<<NB, 256, 0, stream>>>(x, w1p, b1, W2, b2, batch,
                                         recs, hdr, zpart, N);
    combine_kernel<<<NUM_GRAPHS, 256, 0, stream>>>(recs, hdr, zpart, NB,
                                                   batch, N, out);
}